// Round 1
// baseline (282.427 us; speedup 1.0000x reference)
//
#include <hip/hip_runtime.h>
#include <cstdint>
#include <cstddef>

#define B_ 8
#define T_ 2048
#define F_ 512
#define D_ 256

typedef float f32x4 __attribute__((ext_vector_type(4)));
typedef __bf16 bf16x8 __attribute__((ext_vector_type(8)));
typedef unsigned short us8 __attribute__((ext_vector_type(8)));
typedef unsigned short us4 __attribute__((ext_vector_type(4)));

static __device__ __forceinline__ unsigned short f2bf(float f) {
  union { float f; unsigned int u; } v; v.f = f;
  unsigned int u = v.u;
  u += 0x7fffu + ((u >> 16) & 1u);   // RNE
  return (unsigned short)(u >> 16);
}

static __device__ __forceinline__ bf16x8 ldb8(const unsigned short* p) {
  return *reinterpret_cast<const bf16x8*>(p);
}

static __device__ __forceinline__ f32x4 mfma_bf16(bf16x8 a, bf16x8 b, f32x4 c) {
  return __builtin_amdgcn_mfma_f32_16x16x32_bf16(a, b, c, 0, 0, 0);
}

// ---------------------------------------------------------------------------
// Kernel 1: transpose + convert the three W matrices: [F,D] f32 -> [D,F] bf16
// grid (F/64, D/64, 3), block 256
// ---------------------------------------------------------------------------
__global__ __launch_bounds__(256) void tw_kernel(const float* __restrict__ Wq,
                                                 const float* __restrict__ Wk,
                                                 const float* __restrict__ Wv,
                                                 unsigned short* __restrict__ Wt) {
  __shared__ unsigned short tile[64][72];
  const float* W = (blockIdx.z == 0) ? Wq : (blockIdx.z == 1) ? Wk : Wv;
  unsigned short* out = Wt + (size_t)blockIdx.z * (D_ * F_);
  int k0 = blockIdx.x * 64, n0 = blockIdx.y * 64;
  int t = threadIdx.x;
#pragma unroll
  for (int i = 0; i < 4; i++) {
    int c = t + 256 * i;
    int r = c >> 4, c4 = (c & 15) * 4;
    float4 v = *reinterpret_cast<const float4*>(&W[(size_t)(k0 + r) * D_ + n0 + c4]);
    us4 p; p[0] = f2bf(v.x); p[1] = f2bf(v.y); p[2] = f2bf(v.z); p[3] = f2bf(v.w);
    *reinterpret_cast<us4*>(&tile[r][c4]) = p;
  }
  __syncthreads();
#pragma unroll
  for (int i = 0; i < 4; i++) {
    int c = t + 256 * i;
    int r = c >> 4, c4 = (c & 15) * 4;          // r = n-row, c4 = k offset
    us4 p;
    p[0] = tile[c4 + 0][r];
    p[1] = tile[c4 + 1][r];
    p[2] = tile[c4 + 2][r];
    p[3] = tile[c4 + 3][r];
    *reinterpret_cast<us4*>(&out[(size_t)(n0 + r) * F_ + k0 + c4]) = p;
  }
}

// ---------------------------------------------------------------------------
// Kernel 2: projection GEMM.  out = X[16384,512] * W  (per z: Q/16, K, V^T)
// grid (128, 2, 3): M-tile 128, N-tile 128, z = {Q,K,V}. block 256 (4 waves)
// ---------------------------------------------------------------------------
__global__ __launch_bounds__(256) void proj_kernel(const float* __restrict__ X,
                                                   const unsigned short* __restrict__ Wt,
                                                   unsigned short* __restrict__ Qs,
                                                   unsigned short* __restrict__ Kb,
                                                   unsigned short* __restrict__ Vt) {
  __shared__ unsigned short Al[128][72];
  __shared__ unsigned short Bl[128][72];
  const int brow = blockIdx.x * 128;
  const int bcol = blockIdx.y * 128;
  const int z = blockIdx.z;
  const unsigned short* W = Wt + (size_t)z * (D_ * F_);
  const int tid = threadIdx.x;
  const int wave = tid >> 6, lane = tid & 63;
  const int wr = wave >> 1, wc = wave & 1;
  const int lg = lane >> 4, lr = lane & 15;

  f32x4 acc[4][4] = {};

  for (int k0 = 0; k0 < F_; k0 += 64) {
    // stage A (X tile, fp32 -> bf16) and B (Wt tile, already bf16)
#pragma unroll
    for (int i = 0; i < 4; i++) {
      int c = tid + 256 * i;
      int r = c >> 3, off = (c & 7) * 8;
      float4 v0 = *reinterpret_cast<const float4*>(&X[(size_t)(brow + r) * F_ + k0 + off]);
      float4 v1 = *reinterpret_cast<const float4*>(&X[(size_t)(brow + r) * F_ + k0 + off + 4]);
      us8 p;
      p[0] = f2bf(v0.x); p[1] = f2bf(v0.y); p[2] = f2bf(v0.z); p[3] = f2bf(v0.w);
      p[4] = f2bf(v1.x); p[5] = f2bf(v1.y); p[6] = f2bf(v1.z); p[7] = f2bf(v1.w);
      *reinterpret_cast<us8*>(&Al[r][off]) = p;
      *reinterpret_cast<us8*>(&Bl[r][off]) =
          *reinterpret_cast<const us8*>(&W[(size_t)(bcol + r) * F_ + k0 + off]);
    }
    __syncthreads();
#pragma unroll
    for (int kk = 0; kk < 2; kk++) {
      bf16x8 af[4], bfr[4];
#pragma unroll
      for (int mi = 0; mi < 4; mi++) af[mi] = ldb8(&Al[wr * 64 + mi * 16 + lr][kk * 32 + lg * 8]);
#pragma unroll
      for (int ni = 0; ni < 4; ni++) bfr[ni] = ldb8(&Bl[wc * 64 + ni * 16 + lr][kk * 32 + lg * 8]);
#pragma unroll
      for (int mi = 0; mi < 4; mi++)
#pragma unroll
        for (int ni = 0; ni < 4; ni++)
          acc[mi][ni] = mfma_bf16(af[mi], bfr[ni], acc[mi][ni]);
    }
    __syncthreads();
  }

  // epilogue.  D-frag: row = 4*lg + j, col = lr
#pragma unroll
  for (int mi = 0; mi < 4; mi++) {
#pragma unroll
    for (int ni = 0; ni < 4; ni++) {
      int row0 = brow + wr * 64 + mi * 16 + lg * 4;
      int col = bcol + wc * 64 + ni * 16 + lr;
      if (z == 0) {
#pragma unroll
        for (int j = 0; j < 4; j++)
          Qs[(size_t)(row0 + j) * D_ + col] = f2bf(acc[mi][ni][j] * 0.0625f);  // fold 1/sqrt(256)
      } else if (z == 1) {
#pragma unroll
        for (int j = 0; j < 4; j++)
          Kb[(size_t)(row0 + j) * D_ + col] = f2bf(acc[mi][ni][j]);
      } else {
        int b = row0 >> 11, t0 = row0 & (T_ - 1);
        us4 p;
#pragma unroll
        for (int j = 0; j < 4; j++) p[j] = f2bf(acc[mi][ni][j]);
        *reinterpret_cast<us4*>(&Vt[(size_t)b * D_ * T_ + (size_t)col * T_ + t0]) = p;
      }
    }
  }
}

// ---------------------------------------------------------------------------
// Kernel 3: flash attention.  grid (T/64, B), block 256 (4 waves x 16 q-rows)
// Qs already scaled by 1/16. Vt is [B][D][T].
// ---------------------------------------------------------------------------
#define KVB 64
__global__ __launch_bounds__(256) void flash_kernel(const unsigned short* __restrict__ Qs,
                                                    const unsigned short* __restrict__ Kb,
                                                    const unsigned short* __restrict__ Vt,
                                                    float* __restrict__ out) {
  __shared__ unsigned short Kl[KVB][264];    // [kv][d], padded
  __shared__ unsigned short Vl[D_][72];      // [d][kv], padded (V^T tile)
  __shared__ unsigned short Pl[4][16][72];   // per-wave P relayout buffer

  const int qt = blockIdx.x, b = blockIdx.y;
  const int tid = threadIdx.x;
  const int wave = tid >> 6, lane = tid & 63;
  const int lg = lane >> 4, lr = lane & 15;

  const int qrow = qt * 64 + wave * 16 + lr;
  const unsigned short* qptr = Qs + ((size_t)b * T_ + qrow) * D_;
  bf16x8 qf[8];
#pragma unroll
  for (int ks = 0; ks < 8; ks++) qf[ks] = ldb8(qptr + ks * 32 + lg * 8);

  f32x4 o[16] = {};
  float m[4] = {-__builtin_inff(), -__builtin_inff(), -__builtin_inff(), -__builtin_inff()};
  float lsum[4] = {0.f, 0.f, 0.f, 0.f};

  const unsigned short* kbase = Kb + (size_t)b * T_ * D_;
  const unsigned short* vbase = Vt + (size_t)b * D_ * T_;

  for (int kt = 0; kt < T_ / KVB; kt++) {
    // ---- stage K tile [64][256] and V^T tile [256][64] ----
#pragma unroll
    for (int i = 0; i < 8; i++) {
      int c = tid + 256 * i;
      int r = c >> 5, off = (c & 31) * 8;
      *reinterpret_cast<us8*>(&Kl[r][off]) =
          *reinterpret_cast<const us8*>(&kbase[(size_t)(kt * KVB + r) * D_ + off]);
      int r2 = c >> 3, off2 = (c & 7) * 8;
      *reinterpret_cast<us8*>(&Vl[r2][off2]) =
          *reinterpret_cast<const us8*>(&vbase[(size_t)r2 * T_ + kt * KVB + off2]);
    }
    __syncthreads();

    // ---- S = Q * K^T  (16q x 64k per wave) ----
    f32x4 s[4] = {};
#pragma unroll
    for (int ks = 0; ks < 8; ks++) {
#pragma unroll
      for (int nf = 0; nf < 4; nf++) {
        bf16x8 kb = ldb8(&Kl[nf * 16 + lr][ks * 32 + lg * 8]);
        s[nf] = mfma_bf16(qf[ks], kb, s[nf]);
      }
    }

    // ---- online softmax (rows live in one 16-lane group, reg j) ----
    float corr[4];
#pragma unroll
    for (int j = 0; j < 4; j++) {
      float t0 = fmaxf(fmaxf(s[0][j], s[1][j]), fmaxf(s[2][j], s[3][j]));
      t0 = fmaxf(t0, __shfl_xor(t0, 1));
      t0 = fmaxf(t0, __shfl_xor(t0, 2));
      t0 = fmaxf(t0, __shfl_xor(t0, 4));
      t0 = fmaxf(t0, __shfl_xor(t0, 8));
      float mn = fmaxf(m[j], t0);
      corr[j] = __expf(m[j] - mn);
      m[j] = mn;
    }
    float rs[4] = {0.f, 0.f, 0.f, 0.f};
#pragma unroll
    for (int nf = 0; nf < 4; nf++) {
#pragma unroll
      for (int j = 0; j < 4; j++) {
        float p = __expf(s[nf][j] - m[j]);
        rs[j] += p;
        Pl[wave][lg * 4 + j][nf * 16 + lr] = f2bf(p);
      }
    }
#pragma unroll
    for (int j = 0; j < 4; j++) {
      float t0 = rs[j];
      t0 += __shfl_xor(t0, 1);
      t0 += __shfl_xor(t0, 2);
      t0 += __shfl_xor(t0, 4);
      t0 += __shfl_xor(t0, 8);
      lsum[j] = lsum[j] * corr[j] + t0;
    }
#pragma unroll
    for (int nf = 0; nf < 16; nf++) {
#pragma unroll
      for (int j = 0; j < 4; j++) o[nf][j] *= corr[j];
    }

    // ---- O += P * V ----
#pragma unroll
    for (int ks = 0; ks < 2; ks++) {
      bf16x8 pa = ldb8(&Pl[wave][lr][ks * 32 + lg * 8]);
#pragma unroll
      for (int nf = 0; nf < 16; nf++) {
        bf16x8 vb = ldb8(&Vl[nf * 16 + lr][ks * 32 + lg * 8]);
        o[nf] = mfma_bf16(pa, vb, o[nf]);
      }
    }
    __syncthreads();
  }

  // ---- normalize + write fp32 out ----
  float inv[4];
#pragma unroll
  for (int j = 0; j < 4; j++) inv[j] = 1.0f / lsum[j];
#pragma unroll
  for (int nf = 0; nf < 16; nf++) {
#pragma unroll
    for (int j = 0; j < 4; j++) {
      int q = qt * 64 + wave * 16 + lg * 4 + j;
      int d = nf * 16 + lr;
      out[((size_t)b * T_ + q) * D_ + d] = o[nf][j] * inv[j];
    }
  }
}

// ---------------------------------------------------------------------------
extern "C" void kernel_launch(void* const* d_in, const int* in_sizes, int n_in,
                              void* d_out, int out_size, void* d_ws, size_t ws_size,
                              hipStream_t stream) {
  const float* X  = (const float*)d_in[0];
  const float* Wq = (const float*)d_in[1];
  const float* Wk = (const float*)d_in[2];
  const float* Wv = (const float*)d_in[3];
  float* out = (float*)d_out;

  char* ws = (char*)d_ws;
  // layout: Wt (3*256*512*2 = 786432) | Qs (8MB) | Kb (8MB) | Vt (8MB)  ~ 25.7MB
  unsigned short* Wt = (unsigned short*)ws;
  unsigned short* Qs = (unsigned short*)(ws + 786432);
  unsigned short* Kb = (unsigned short*)(ws + 786432 + 8388608);
  unsigned short* Vt = (unsigned short*)(ws + 786432 + 2 * 8388608);

  tw_kernel<<<dim3(F_ / 64, D_ / 64, 3), 256, 0, stream>>>(Wq, Wk, Wv, Wt);
  proj_kernel<<<dim3((B_ * T_) / 128, D_ / 128, 3), 256, 0, stream>>>(X, Wt, Qs, Kb, Vt);
  flash_kernel<<<dim3(T_ / 64, B_), 256, 0, stream>>>(Qs, Kb, Vt, out);
}